// Round 1
// baseline (1079.712 us; speedup 1.0000x reference)
//
#include <hip/hip_runtime.h>

// LightGCN: N=150000 nodes, D=64, E=1200000 edges, 3 propagation layers.
// out = (emb + x1 + x2 + x3) / 4, where x_{k+1}[c] = sum_e norm[e]*x_k[row[e]] for col[e]==c.

constexpr int NUM_USERS = 100000;
constexpr int NUM_ITEMS = 50000;
constexpr int N_NODES   = NUM_USERS + NUM_ITEMS;   // 150000
constexpr int EMBED_DIM = 64;
constexpr int NUM_EDGES = 1200000;

// ---------------- degree accumulation ----------------
__global__ void deg_kernel(const int* __restrict__ row, const int* __restrict__ col,
                           float* __restrict__ deg_row, float* __restrict__ deg_col) {
    int e = blockIdx.x * blockDim.x + threadIdx.x;
    if (e < NUM_EDGES) {
        atomicAdd(&deg_row[row[e]], 1.0f);
        atomicAdd(&deg_col[col[e]], 1.0f);
    }
}

// deg -> deg^{-1/2} in place (0 if deg==0)
__global__ void inv_kernel(float* __restrict__ deg_row, float* __restrict__ deg_col) {
    int i = blockIdx.x * blockDim.x + threadIdx.x;
    if (i < N_NODES) {
        float a = deg_row[i];
        deg_row[i] = (a > 0.0f) ? rsqrtf(a) : 0.0f;
        float b = deg_col[i];
        deg_col[i] = (b > 0.0f) ? rsqrtf(b) : 0.0f;
    }
}

// norm[e] = inv_row[row[e]] * inv_col[col[e]]
__global__ void norm_kernel(const int* __restrict__ row, const int* __restrict__ col,
                            const float* __restrict__ inv_row, const float* __restrict__ inv_col,
                            float* __restrict__ norm) {
    int e = blockIdx.x * blockDim.x + threadIdx.x;
    if (e < NUM_EDGES) {
        norm[e] = inv_row[row[e]] * inv_col[col[e]];
    }
}

// x0 = emb; accum = emb  (vectorized float4)
__global__ void init_kernel(const float4* __restrict__ emb, float4* __restrict__ x0,
                            float4* __restrict__ accum) {
    int i = blockIdx.x * blockDim.x + threadIdx.x;
    constexpr int n4 = N_NODES * EMBED_DIM / 4;
    if (i < n4) {
        float4 v = emb[i];
        x0[i] = v;
        accum[i] = v;
    }
}

// One 64-lane group per edge; lane d handles dim d.
// xn[col[e]][d] += norm[e] * x[row[e]][d]
__global__ void scatter_kernel(const int* __restrict__ row, const int* __restrict__ col,
                               const float* __restrict__ norm,
                               const float* __restrict__ x, float* __restrict__ xn) {
    const int edges_per_block = blockDim.x >> 6;       // 256 threads -> 4 edges
    int e = blockIdx.x * edges_per_block + (threadIdx.x >> 6);
    int d = threadIdx.x & 63;
    if (e < NUM_EDGES) {
        float nv = norm[e];
        int r = row[e];
        int c = col[e];
        float v = nv * x[r * EMBED_DIM + d];
        atomicAdd(&xn[c * EMBED_DIM + d], v);
    }
}

// accum = (accum + x) * scale   (scale=1 for intermediate layers, 0.25 on the last)
__global__ void add_kernel(float4* __restrict__ accum, const float4* __restrict__ x, float scale) {
    int i = blockIdx.x * blockDim.x + threadIdx.x;
    constexpr int n4 = N_NODES * EMBED_DIM / 4;
    if (i < n4) {
        float4 a = accum[i];
        float4 v = x[i];
        a.x = (a.x + v.x) * scale;
        a.y = (a.y + v.y) * scale;
        a.z = (a.z + v.z) * scale;
        a.w = (a.w + v.w) * scale;
        accum[i] = a;
    }
}

extern "C" void kernel_launch(void* const* d_in, const int* in_sizes, int n_in,
                              void* d_out, int out_size, void* d_ws, size_t ws_size,
                              hipStream_t stream) {
    const int*   edge_index = (const int*)d_in[0];   // [2, E]
    const float* embedding  = (const float*)d_in[1]; // [N, 64]
    const int* row = edge_index;                      // edge_index[0]
    const int* col = edge_index + NUM_EDGES;          // edge_index[1]
    float* out = (float*)d_out;                       // [N, 64] accum lives here

    // Workspace carve-up (all fp32), 256B-aligned regions.
    // deg_row: N, deg_col: N, norm: E, x0: N*D, x1: N*D  => ~82.8 MB
    char* ws = (char*)d_ws;
    auto align_up = [](size_t v) { return (v + 255) & ~size_t(255); };
    size_t off = 0;
    float* deg_row = (float*)(ws + off); off = align_up(off + sizeof(float) * N_NODES);
    float* deg_col = (float*)(ws + off); off = align_up(off + sizeof(float) * N_NODES);
    float* norm    = (float*)(ws + off); off = align_up(off + sizeof(float) * NUM_EDGES);
    float* x0      = (float*)(ws + off); off = align_up(off + sizeof(float) * N_NODES * EMBED_DIM);
    float* x1      = (float*)(ws + off); off = align_up(off + sizeof(float) * N_NODES * EMBED_DIM);

    const size_t xbytes = sizeof(float) * N_NODES * EMBED_DIM;

    // 1) degrees
    hipMemsetAsync(deg_row, 0, sizeof(float) * N_NODES, stream);
    hipMemsetAsync(deg_col, 0, sizeof(float) * N_NODES, stream);
    {
        int threads = 256, blocks = (NUM_EDGES + threads - 1) / threads;
        deg_kernel<<<blocks, threads, 0, stream>>>(row, col, deg_row, deg_col);
    }
    // 2) inv sqrt degrees
    {
        int threads = 256, blocks = (N_NODES + threads - 1) / threads;
        inv_kernel<<<blocks, threads, 0, stream>>>(deg_row, deg_col);
    }
    // 3) per-edge norm
    {
        int threads = 256, blocks = (NUM_EDGES + threads - 1) / threads;
        norm_kernel<<<blocks, threads, 0, stream>>>(row, col, deg_row, deg_col, norm);
    }
    // 4) init x0 = accum = embedding
    {
        constexpr int n4 = N_NODES * EMBED_DIM / 4;
        int threads = 256, blocks = (n4 + threads - 1) / threads;
        init_kernel<<<blocks, threads, 0, stream>>>((const float4*)embedding,
                                                    (float4*)x0, (float4*)out);
    }

    // 5) three propagation layers (ping-pong x0 <-> x1)
    float* x_cur = x0;
    float* x_nxt = x1;
    for (int layer = 0; layer < 3; ++layer) {
        hipMemsetAsync(x_nxt, 0, xbytes, stream);
        {
            int threads = 256;                          // 4 edges/block
            int epb = threads / 64;
            int blocks = (NUM_EDGES + epb - 1) / epb;
            scatter_kernel<<<blocks, threads, 0, stream>>>(row, col, norm, x_cur, x_nxt);
        }
        {
            constexpr int n4 = N_NODES * EMBED_DIM / 4;
            int threads = 256, blocks = (n4 + threads - 1) / threads;
            float scale = (layer == 2) ? 0.25f : 1.0f;
            add_kernel<<<blocks, threads, 0, stream>>>((float4*)out, (const float4*)x_nxt, scale);
        }
        float* t = x_cur; x_cur = x_nxt; x_nxt = t;
    }
}

// Round 2
// 645.846 us; speedup vs baseline: 1.6718x; 1.6718x over previous
//
#include <hip/hip_runtime.h>

// LightGCN via destination-sorted CSR + gather (no per-edge atomics in layers).
// out = (emb + x1 + x2 + x3)/4,  x_{k+1}[c] = inv_col[c] * sum_{e: col=c} inv_row[row_e] * x_k[row_e]

constexpr int NUM_USERS = 100000;
constexpr int NUM_ITEMS = 50000;
constexpr int N_NODES   = NUM_USERS + NUM_ITEMS;   // 150000
constexpr int EMBED_DIM = 64;
constexpr int NUM_EDGES = 1200000;
constexpr int SCAN_CHUNK = 1024;                   // elements per scan block
constexpr int NUM_SCAN_BLOCKS = (N_NODES + SCAN_CHUNK - 1) / SCAN_CHUNK;  // 147

// ---- histogram of row and col (int atomics) ----
__global__ void hist_kernel(const int* __restrict__ row, const int* __restrict__ col,
                            int* __restrict__ cnt_row, int* __restrict__ cnt_col) {
    int e = blockIdx.x * blockDim.x + threadIdx.x;
    if (e < NUM_EDGES) {
        atomicAdd(&cnt_row[row[e]], 1);
        atomicAdd(&cnt_col[col[e]], 1);
    }
}

// ---- scan stage 1: per-block sums of cnt_col ----
__global__ void scan_block_sums(const int* __restrict__ cnt, int* __restrict__ block_sums) {
    __shared__ int sdata[256];
    int t = threadIdx.x;
    int base = blockIdx.x * SCAN_CHUNK + t * 4;
    int s = 0;
#pragma unroll
    for (int k = 0; k < 4; ++k) { int i = base + k; if (i < N_NODES) s += cnt[i]; }
    sdata[t] = s; __syncthreads();
    for (int off = 128; off > 0; off >>= 1) {
        if (t < off) sdata[t] += sdata[t + off];
        __syncthreads();
    }
    if (t == 0) block_sums[blockIdx.x] = sdata[0];
}

// ---- scan stage 2: exclusive scan of the 147 block sums (single block) ----
__global__ void scan_block_offsets(int* __restrict__ block_sums) {
    __shared__ int sdata[256];
    int t = threadIdx.x;
    int v = (t < NUM_SCAN_BLOCKS) ? block_sums[t] : 0;
    sdata[t] = v; __syncthreads();
    for (int off = 1; off < 256; off <<= 1) {
        int tv = (t >= off) ? sdata[t - off] : 0;
        __syncthreads();
        sdata[t] += tv;
        __syncthreads();
    }
    if (t < NUM_SCAN_BLOCKS) block_sums[t] = sdata[t] - v;   // exclusive
}

// ---- scan stage 3: per-block exclusive scan + global offset -> col_ptr ----
__global__ void scan_final(const int* __restrict__ cnt, const int* __restrict__ block_sums,
                           int* __restrict__ ptr) {
    __shared__ int sdata[256];
    int t = threadIdx.x;
    int base = blockIdx.x * SCAN_CHUNK + t * 4;
    int v[4]; int s = 0;
#pragma unroll
    for (int k = 0; k < 4; ++k) { int i = base + k; v[k] = (i < N_NODES) ? cnt[i] : 0; s += v[k]; }
    sdata[t] = s; __syncthreads();
    for (int off = 1; off < 256; off <<= 1) {
        int tv = (t >= off) ? sdata[t - off] : 0;
        __syncthreads();
        sdata[t] += tv;
        __syncthreads();
    }
    int excl = sdata[t] - s + block_sums[blockIdx.x];
#pragma unroll
    for (int k = 0; k < 4; ++k) {
        int i = base + k;
        if (i < N_NODES) { ptr[i] = excl; excl += v[k]; }
    }
}

// ---- int counts -> rsqrt floats, in place ----
__global__ void inv_kernel(int* __restrict__ cnt_row, int* __restrict__ cnt_col) {
    int i = blockIdx.x * blockDim.x + threadIdx.x;
    if (i < N_NODES) {
        int a = cnt_row[i];
        ((float*)cnt_row)[i] = (a > 0) ? rsqrtf((float)a) : 0.0f;
        int b = cnt_col[i];
        ((float*)cnt_col)[i] = (b > 0) ? rsqrtf((float)b) : 0.0f;
    }
}

// ---- counting-sort fill: advance col_ptr cursors; afterwards ptr[c] == orig ptr[c+1] ----
__global__ void fill_kernel(const int* __restrict__ row, const int* __restrict__ col,
                            int* __restrict__ ptr, int* __restrict__ sorted_src) {
    int e = blockIdx.x * blockDim.x + threadIdx.x;
    if (e < NUM_EDGES) {
        int c = col[e];
        int pos = atomicAdd(&ptr[c], 1);
        sorted_src[pos] = row[e];
    }
}

// ---- one wave per destination node; lane = dim ----
// mode 0: x_dst = acc; out = emb + acc          (layer 1, also initializes out)
// mode 1: x_dst = acc; out += acc               (layer 2)
// mode 2: out = (out + acc) * 0.25              (layer 3, final average)
__global__ void layer_kernel(const int* __restrict__ ptr_shifted,
                             const int* __restrict__ sorted_src,
                             const float* __restrict__ inv_row,
                             const float* __restrict__ inv_col,
                             const float* __restrict__ x_src,
                             float* __restrict__ x_dst,
                             float* __restrict__ out,
                             const float* __restrict__ emb,
                             int mode) {
    int wid  = (blockIdx.x * blockDim.x + threadIdx.x) >> 6;
    int lane = threadIdx.x & 63;
    if (wid >= N_NODES) return;
    int start = (wid > 0) ? ptr_shifted[wid - 1] : 0;   // post-fill: ptr[c-1] == orig ptr[c]
    int end   = ptr_shifted[wid];                        // post-fill: ptr[c]   == orig ptr[c+1]
    float invc = inv_col[wid];
    float acc = 0.0f;
    for (int j = start; j < end; ++j) {
        int s   = sorted_src[j];          // wave-uniform broadcast load
        float w = inv_row[s];             // broadcast
        acc += w * x_src[s * EMBED_DIM + lane];   // coalesced 256B wave load
    }
    acc *= invc;
    int oi = wid * EMBED_DIM + lane;
    if (mode == 0)      { x_dst[oi] = acc; out[oi] = emb[oi] + acc; }
    else if (mode == 1) { x_dst[oi] = acc; out[oi] += acc; }
    else                { out[oi] = (out[oi] + acc) * 0.25f; }
}

extern "C" void kernel_launch(void* const* d_in, const int* in_sizes, int n_in,
                              void* d_out, int out_size, void* d_ws, size_t ws_size,
                              hipStream_t stream) {
    const int*   edge_index = (const int*)d_in[0];   // [2, E]
    const float* embedding  = (const float*)d_in[1]; // [N, 64]
    const int* row = edge_index;
    const int* col = edge_index + NUM_EDGES;
    float* out = (float*)d_out;

    char* ws = (char*)d_ws;
    auto align_up = [](size_t v) { return (v + 255) & ~size_t(255); };
    size_t off = 0;
    int* cnt_row    = (int*)(ws + off); off = align_up(off + sizeof(int) * N_NODES);
    int* cnt_col    = (int*)(ws + off); off = align_up(off + sizeof(int) * N_NODES);
    int* col_ptr    = (int*)(ws + off); off = align_up(off + sizeof(int) * N_NODES);
    int* block_sums = (int*)(ws + off); off = align_up(off + sizeof(int) * 1024);
    int* sorted_src = (int*)(ws + off); off = align_up(off + sizeof(int) * NUM_EDGES);
    float* x1       = (float*)(ws + off); off = align_up(off + sizeof(float) * N_NODES * EMBED_DIM);
    float* x2       = (float*)(ws + off); off = align_up(off + sizeof(float) * N_NODES * EMBED_DIM);
    // total ~83.4 MB

    // 1) histograms
    hipMemsetAsync(cnt_row, 0, sizeof(int) * N_NODES, stream);
    hipMemsetAsync(cnt_col, 0, sizeof(int) * N_NODES, stream);
    {
        int threads = 256, blocks = (NUM_EDGES + threads - 1) / threads;
        hist_kernel<<<blocks, threads, 0, stream>>>(row, col, cnt_row, cnt_col);
    }
    // 2) exclusive scan of cnt_col -> col_ptr
    scan_block_sums<<<NUM_SCAN_BLOCKS, 256, 0, stream>>>(cnt_col, block_sums);
    scan_block_offsets<<<1, 256, 0, stream>>>(block_sums);
    scan_final<<<NUM_SCAN_BLOCKS, 256, 0, stream>>>(cnt_col, block_sums, col_ptr);
    // 3) counts -> rsqrt (in place; after scan so cnt_col ints are no longer needed)
    {
        int threads = 256, blocks = (N_NODES + threads - 1) / threads;
        inv_kernel<<<blocks, threads, 0, stream>>>(cnt_row, cnt_col);
    }
    const float* inv_row = (const float*)cnt_row;
    const float* inv_col = (const float*)cnt_col;
    // 4) counting-sort fill (advances col_ptr cursors by one slot per edge)
    {
        int threads = 256, blocks = (NUM_EDGES + threads - 1) / threads;
        fill_kernel<<<blocks, threads, 0, stream>>>(row, col, col_ptr, sorted_src);
    }
    // 5) three gather layers, accum fused into epilogue
    {
        int threads = 256;
        int blocks = (N_NODES * 64 + threads - 1) / threads;   // 37500
        layer_kernel<<<blocks, threads, 0, stream>>>(col_ptr, sorted_src, inv_row, inv_col,
                                                     embedding, x1, out, embedding, 0);
        layer_kernel<<<blocks, threads, 0, stream>>>(col_ptr, sorted_src, inv_row, inv_col,
                                                     x1, x2, out, embedding, 1);
        layer_kernel<<<blocks, threads, 0, stream>>>(col_ptr, sorted_src, inv_row, inv_col,
                                                     x2, x1 /*unused in mode 2*/, out, embedding, 2);
    }
}

// Round 3
// 490.262 us; speedup vs baseline: 2.2023x; 1.3173x over previous
//
#include <hip/hip_runtime.h>

// LightGCN via destination-sorted CSR + gather, latency-optimized inner loop:
// - pre-scaled source matrix y = inv_row ⊙ x  (one load per edge, no inv_row gather)
// - cooperative index load + __shfl broadcast (no per-edge index load)
// - 4-way unrolled gather with independent accumulators (MLP >= 4)

constexpr int NUM_USERS = 100000;
constexpr int NUM_ITEMS = 50000;
constexpr int N_NODES   = NUM_USERS + NUM_ITEMS;   // 150000
constexpr int EMBED_DIM = 64;
constexpr int NUM_EDGES = 1200000;
constexpr int SCAN_CHUNK = 1024;
constexpr int NUM_SCAN_BLOCKS = (N_NODES + SCAN_CHUNK - 1) / SCAN_CHUNK;  // 147

// ---- histogram of row and col ----
__global__ void hist_kernel(const int* __restrict__ row, const int* __restrict__ col,
                            int* __restrict__ cnt_row, int* __restrict__ cnt_col) {
    int e = blockIdx.x * blockDim.x + threadIdx.x;
    if (e < NUM_EDGES) {
        atomicAdd(&cnt_row[row[e]], 1);
        atomicAdd(&cnt_col[col[e]], 1);
    }
}

// ---- scan stage 1: per-block sums of cnt_col ----
__global__ void scan_block_sums(const int* __restrict__ cnt, int* __restrict__ block_sums) {
    __shared__ int sdata[256];
    int t = threadIdx.x;
    int base = blockIdx.x * SCAN_CHUNK + t * 4;
    int s = 0;
#pragma unroll
    for (int k = 0; k < 4; ++k) { int i = base + k; if (i < N_NODES) s += cnt[i]; }
    sdata[t] = s; __syncthreads();
    for (int off = 128; off > 0; off >>= 1) {
        if (t < off) sdata[t] += sdata[t + off];
        __syncthreads();
    }
    if (t == 0) block_sums[blockIdx.x] = sdata[0];
}

// ---- scan stage 2: exclusive scan of block sums (single block) ----
__global__ void scan_block_offsets(int* __restrict__ block_sums) {
    __shared__ int sdata[256];
    int t = threadIdx.x;
    int v = (t < NUM_SCAN_BLOCKS) ? block_sums[t] : 0;
    sdata[t] = v; __syncthreads();
    for (int off = 1; off < 256; off <<= 1) {
        int tv = (t >= off) ? sdata[t - off] : 0;
        __syncthreads();
        sdata[t] += tv;
        __syncthreads();
    }
    if (t < NUM_SCAN_BLOCKS) block_sums[t] = sdata[t] - v;   // exclusive
}

// ---- scan stage 3: per-block exclusive scan + global offset -> col_ptr ----
__global__ void scan_final(const int* __restrict__ cnt, const int* __restrict__ block_sums,
                           int* __restrict__ ptr) {
    __shared__ int sdata[256];
    int t = threadIdx.x;
    int base = blockIdx.x * SCAN_CHUNK + t * 4;
    int v[4]; int s = 0;
#pragma unroll
    for (int k = 0; k < 4; ++k) { int i = base + k; v[k] = (i < N_NODES) ? cnt[i] : 0; s += v[k]; }
    sdata[t] = s; __syncthreads();
    for (int off = 1; off < 256; off <<= 1) {
        int tv = (t >= off) ? sdata[t - off] : 0;
        __syncthreads();
        sdata[t] += tv;
        __syncthreads();
    }
    int excl = sdata[t] - s + block_sums[blockIdx.x];
#pragma unroll
    for (int k = 0; k < 4; ++k) {
        int i = base + k;
        if (i < N_NODES) { ptr[i] = excl; excl += v[k]; }
    }
}

// ---- int counts -> rsqrt floats, in place ----
__global__ void inv_kernel(int* __restrict__ cnt_row, int* __restrict__ cnt_col) {
    int i = blockIdx.x * blockDim.x + threadIdx.x;
    if (i < N_NODES) {
        int a = cnt_row[i];
        ((float*)cnt_row)[i] = (a > 0) ? rsqrtf((float)a) : 0.0f;
        int b = cnt_col[i];
        ((float*)cnt_col)[i] = (b > 0) ? rsqrtf((float)b) : 0.0f;
    }
}

// ---- counting-sort fill ----
__global__ void fill_kernel(const int* __restrict__ row, const int* __restrict__ col,
                            int* __restrict__ ptr, int* __restrict__ sorted_src) {
    int e = blockIdx.x * blockDim.x + threadIdx.x;
    if (e < NUM_EDGES) {
        int c = col[e];
        int pos = atomicAdd(&ptr[c], 1);
        sorted_src[pos] = row[e];
    }
}

// ---- y0[i] = inv_row[i/64] * emb[i] ----
__global__ void init_y_kernel(const float* __restrict__ inv_row,
                              const float* __restrict__ emb, float* __restrict__ y0) {
    int i = blockIdx.x * blockDim.x + threadIdx.x;
    if (i < N_NODES * EMBED_DIM) {
        y0[i] = inv_row[i >> 6] * emb[i];
    }
}

// ---- one wave per destination node; lane = dim ----
// v = inv_col[c] * sum_{e in-edges of c} y[src_e][lane]
// mode 0: y_dst = inv_row[c]*v; out = emb + v
// mode 1: y_dst = inv_row[c]*v; out += v
// mode 2: out = (out + v) * 0.25
__global__ void __launch_bounds__(256, 8)
layer_kernel(const int* __restrict__ ptr_shifted,
             const int* __restrict__ sorted_src,
             const float* __restrict__ inv_row,
             const float* __restrict__ inv_col,
             const float* __restrict__ y_src,
             float* __restrict__ y_dst,
             float* __restrict__ out,
             const float* __restrict__ emb,
             int mode) {
    int wid  = (blockIdx.x * blockDim.x + threadIdx.x) >> 6;
    int lane = threadIdx.x & 63;
    if (wid >= N_NODES) return;
    int start = (wid > 0) ? ptr_shifted[wid - 1] : 0;   // post-fill shift-by-one
    int end   = ptr_shifted[wid];

    float a0 = 0.0f, a1 = 0.0f, a2 = 0.0f, a3 = 0.0f;
    for (int base = start; base < end; base += 64) {
        int cnt = end - base;
        if (cnt > 64) cnt = 64;
        // cooperative coalesced index load: lane j holds sorted_src[base+j]
        int idx = sorted_src[base + ((lane < cnt) ? lane : 0)];
        int j = 0;
        for (; j + 4 <= cnt; j += 4) {
            int s0 = __shfl(idx, j);
            int s1 = __shfl(idx, j + 1);
            int s2 = __shfl(idx, j + 2);
            int s3 = __shfl(idx, j + 3);
            float v0 = y_src[s0 * EMBED_DIM + lane];
            float v1 = y_src[s1 * EMBED_DIM + lane];
            float v2 = y_src[s2 * EMBED_DIM + lane];
            float v3 = y_src[s3 * EMBED_DIM + lane];
            a0 += v0; a1 += v1; a2 += v2; a3 += v3;
        }
        for (; j < cnt; ++j) {
            int s = __shfl(idx, j);
            a0 += y_src[s * EMBED_DIM + lane];
        }
    }
    float v = ((a0 + a1) + (a2 + a3)) * inv_col[wid];
    int oi = wid * EMBED_DIM + lane;
    if (mode == 0)      { y_dst[oi] = inv_row[wid] * v; out[oi] = emb[oi] + v; }
    else if (mode == 1) { y_dst[oi] = inv_row[wid] * v; out[oi] += v; }
    else                { out[oi] = (out[oi] + v) * 0.25f; }
}

extern "C" void kernel_launch(void* const* d_in, const int* in_sizes, int n_in,
                              void* d_out, int out_size, void* d_ws, size_t ws_size,
                              hipStream_t stream) {
    const int*   edge_index = (const int*)d_in[0];   // [2, E]
    const float* embedding  = (const float*)d_in[1]; // [N, 64]
    const int* row = edge_index;
    const int* col = edge_index + NUM_EDGES;
    float* out = (float*)d_out;

    char* ws = (char*)d_ws;
    auto align_up = [](size_t v) { return (v + 255) & ~size_t(255); };
    size_t off = 0;
    int* cnt_row    = (int*)(ws + off); off = align_up(off + sizeof(int) * N_NODES);
    int* cnt_col    = (int*)(ws + off); off = align_up(off + sizeof(int) * N_NODES);
    int* col_ptr    = (int*)(ws + off); off = align_up(off + sizeof(int) * N_NODES);
    int* block_sums = (int*)(ws + off); off = align_up(off + sizeof(int) * 1024);
    int* sorted_src = (int*)(ws + off); off = align_up(off + sizeof(int) * NUM_EDGES);
    float* ya       = (float*)(ws + off); off = align_up(off + sizeof(float) * N_NODES * EMBED_DIM);
    float* yb       = (float*)(ws + off); off = align_up(off + sizeof(float) * N_NODES * EMBED_DIM);

    // 1) histograms
    hipMemsetAsync(cnt_row, 0, sizeof(int) * N_NODES, stream);
    hipMemsetAsync(cnt_col, 0, sizeof(int) * N_NODES, stream);
    {
        int threads = 256, blocks = (NUM_EDGES + threads - 1) / threads;
        hist_kernel<<<blocks, threads, 0, stream>>>(row, col, cnt_row, cnt_col);
    }
    // 2) exclusive scan of cnt_col -> col_ptr
    scan_block_sums<<<NUM_SCAN_BLOCKS, 256, 0, stream>>>(cnt_col, block_sums);
    scan_block_offsets<<<1, 256, 0, stream>>>(block_sums);
    scan_final<<<NUM_SCAN_BLOCKS, 256, 0, stream>>>(cnt_col, block_sums, col_ptr);
    // 3) counts -> rsqrt
    {
        int threads = 256, blocks = (N_NODES + threads - 1) / threads;
        inv_kernel<<<blocks, threads, 0, stream>>>(cnt_row, cnt_col);
    }
    const float* inv_row = (const float*)cnt_row;
    const float* inv_col = (const float*)cnt_col;
    // 4) counting-sort fill
    {
        int threads = 256, blocks = (NUM_EDGES + threads - 1) / threads;
        fill_kernel<<<blocks, threads, 0, stream>>>(row, col, col_ptr, sorted_src);
    }
    // 5) y0 = inv_row ⊙ emb
    {
        int threads = 256, blocks = (N_NODES * EMBED_DIM + threads - 1) / threads;
        init_y_kernel<<<blocks, threads, 0, stream>>>(inv_row, embedding, ya);
    }
    // 6) three gather layers (y ping-pong: ya -> yb -> ya)
    {
        int threads = 256;
        int blocks = (N_NODES * 64 + threads - 1) / threads;   // 37500
        layer_kernel<<<blocks, threads, 0, stream>>>(col_ptr, sorted_src, inv_row, inv_col,
                                                     ya, yb, out, embedding, 0);
        layer_kernel<<<blocks, threads, 0, stream>>>(col_ptr, sorted_src, inv_row, inv_col,
                                                     yb, ya, out, embedding, 1);
        layer_kernel<<<blocks, threads, 0, stream>>>(col_ptr, sorted_src, inv_row, inv_col,
                                                     ya, yb /*unused*/, out, embedding, 2);
    }
}

// Round 4
// 460.378 us; speedup vs baseline: 2.3453x; 1.0649x over previous
//
#include <hip/hip_runtime.h>
#include <hip/hip_fp16.h>

// LightGCN via destination-sorted CSR + gather.
// This round: fp16 intermediate y = inv_row ⊙ x (half the gather bytes/lines),
// wave processes 2 edges concurrently (lane halves), 2-deep unroll (4 edges in flight).

constexpr int NUM_USERS = 100000;
constexpr int NUM_ITEMS = 50000;
constexpr int N_NODES   = NUM_USERS + NUM_ITEMS;   // 150000
constexpr int EMBED_DIM = 64;
constexpr int NUM_EDGES = 1200000;
constexpr int SCAN_CHUNK = 1024;
constexpr int NUM_SCAN_BLOCKS = (N_NODES + SCAN_CHUNK - 1) / SCAN_CHUNK;  // 147

// ---- histogram of row and col ----
__global__ void hist_kernel(const int* __restrict__ row, const int* __restrict__ col,
                            int* __restrict__ cnt_row, int* __restrict__ cnt_col) {
    int e = blockIdx.x * blockDim.x + threadIdx.x;
    if (e < NUM_EDGES) {
        atomicAdd(&cnt_row[row[e]], 1);
        atomicAdd(&cnt_col[col[e]], 1);
    }
}

// ---- scan stage 1: per-block sums of cnt_col ----
__global__ void scan_block_sums(const int* __restrict__ cnt, int* __restrict__ block_sums) {
    __shared__ int sdata[256];
    int t = threadIdx.x;
    int base = blockIdx.x * SCAN_CHUNK + t * 4;
    int s = 0;
#pragma unroll
    for (int k = 0; k < 4; ++k) { int i = base + k; if (i < N_NODES) s += cnt[i]; }
    sdata[t] = s; __syncthreads();
    for (int off = 128; off > 0; off >>= 1) {
        if (t < off) sdata[t] += sdata[t + off];
        __syncthreads();
    }
    if (t == 0) block_sums[blockIdx.x] = sdata[0];
}

// ---- scan stage 2: exclusive scan of block sums (single block) ----
__global__ void scan_block_offsets(int* __restrict__ block_sums) {
    __shared__ int sdata[256];
    int t = threadIdx.x;
    int v = (t < NUM_SCAN_BLOCKS) ? block_sums[t] : 0;
    sdata[t] = v; __syncthreads();
    for (int off = 1; off < 256; off <<= 1) {
        int tv = (t >= off) ? sdata[t - off] : 0;
        __syncthreads();
        sdata[t] += tv;
        __syncthreads();
    }
    if (t < NUM_SCAN_BLOCKS) block_sums[t] = sdata[t] - v;   // exclusive
}

// ---- scan stage 3: per-block exclusive scan + global offset -> col_ptr ----
__global__ void scan_final(const int* __restrict__ cnt, const int* __restrict__ block_sums,
                           int* __restrict__ ptr) {
    __shared__ int sdata[256];
    int t = threadIdx.x;
    int base = blockIdx.x * SCAN_CHUNK + t * 4;
    int v[4]; int s = 0;
#pragma unroll
    for (int k = 0; k < 4; ++k) { int i = base + k; v[k] = (i < N_NODES) ? cnt[i] : 0; s += v[k]; }
    sdata[t] = s; __syncthreads();
    for (int off = 1; off < 256; off <<= 1) {
        int tv = (t >= off) ? sdata[t - off] : 0;
        __syncthreads();
        sdata[t] += tv;
        __syncthreads();
    }
    int excl = sdata[t] - s + block_sums[blockIdx.x];
#pragma unroll
    for (int k = 0; k < 4; ++k) {
        int i = base + k;
        if (i < N_NODES) { ptr[i] = excl; excl += v[k]; }
    }
}

// ---- int counts -> rsqrt floats, in place ----
__global__ void inv_kernel(int* __restrict__ cnt_row, int* __restrict__ cnt_col) {
    int i = blockIdx.x * blockDim.x + threadIdx.x;
    if (i < N_NODES) {
        int a = cnt_row[i];
        ((float*)cnt_row)[i] = (a > 0) ? rsqrtf((float)a) : 0.0f;
        int b = cnt_col[i];
        ((float*)cnt_col)[i] = (b > 0) ? rsqrtf((float)b) : 0.0f;
    }
}

// ---- counting-sort fill ----
__global__ void fill_kernel(const int* __restrict__ row, const int* __restrict__ col,
                            int* __restrict__ ptr, int* __restrict__ sorted_src) {
    int e = blockIdx.x * blockDim.x + threadIdx.x;
    if (e < NUM_EDGES) {
        int c = col[e];
        int pos = atomicAdd(&ptr[c], 1);
        sorted_src[pos] = row[e];
    }
}

// ---- y0 (fp16) = inv_row ⊙ emb ; one half2 (2 dims) per thread ----
__global__ void init_y_kernel(const float* __restrict__ inv_row,
                              const float2* __restrict__ emb2, __half2* __restrict__ y0) {
    int i = blockIdx.x * blockDim.x + threadIdx.x;     // over N*32
    if (i < N_NODES * (EMBED_DIM / 2)) {
        float w = inv_row[i >> 5];
        float2 e = emb2[i];
        y0[i] = __floats2half2_rn(w * e.x, w * e.y);
    }
}

// ---- one wave per destination node ----
// Lane layout: eh = lane>>5 (which of 2 concurrent edges), d2 = lane&31 (dim pair).
// v[c][:] = inv_col[c] * sum_{e: col=c} y[src_e][:]
// mode 0: y_dst = h(inv_row[c]*v); out = emb + v
// mode 1: y_dst = h(inv_row[c]*v); out += v
// mode 2: out = (out + v) * 0.25
__global__ void __launch_bounds__(256, 8)
layer_kernel(const int* __restrict__ ptr_shifted,
             const int* __restrict__ sorted_src,
             const float* __restrict__ inv_row,
             const float* __restrict__ inv_col,
             const __half2* __restrict__ y_src,
             __half2* __restrict__ y_dst,
             float2* __restrict__ out2,
             const float2* __restrict__ emb2,
             int mode) {
    int wid  = (blockIdx.x * blockDim.x + threadIdx.x) >> 6;
    int lane = threadIdx.x & 63;
    if (wid >= N_NODES) return;
    int d2 = lane & 31;
    int eh = lane >> 5;
    int start = (wid > 0) ? ptr_shifted[wid - 1] : 0;   // post-fill shift-by-one
    int end   = ptr_shifted[wid];

    float ax0 = 0.0f, ay0 = 0.0f, ax1 = 0.0f, ay1 = 0.0f;
    for (int base = start; base < end; base += 64) {
        int cnt = end - base;
        if (cnt > 64) cnt = 64;
        // cooperative coalesced index load: lane j holds sorted_src[base+j]
        int idx = sorted_src[base + ((lane < cnt) ? lane : 0)];
        int j = 0;
        for (; j + 4 <= cnt; j += 4) {
            int sA = __shfl(idx, j + eh);          // edges j, j+1 across lane halves
            int sB = __shfl(idx, j + 2 + eh);      // edges j+2, j+3
            float2 vA = __half22float2(y_src[sA * 32 + d2]);
            float2 vB = __half22float2(y_src[sB * 32 + d2]);
            ax0 += vA.x; ay0 += vA.y;
            ax1 += vB.x; ay1 += vB.y;
        }
        // tail (0..3 edges), predicated — no divergent shfl
        for (; j < cnt; j += 2) {
            int jj = j + eh;
            int sA = __shfl(idx, (jj < cnt) ? jj : 0);
            float2 vA = __half22float2(y_src[sA * 32 + d2]);
            if (jj < cnt) { ax0 += vA.x; ay0 += vA.y; }
        }
    }
    float sx = ax0 + ax1;
    float sy = ay0 + ay1;
    // combine the two lane halves (each holds half the edges for the same dim pair)
    sx += __shfl_xor(sx, 32);
    sy += __shfl_xor(sy, 32);

    float invc = inv_col[wid];
    float vx = sx * invc, vy = sy * invc;

    if (lane < 32) {                       // lanes 0-31 hold all dim pairs
        int oi2 = wid * 32 + d2;
        if (mode == 0) {
            float w = inv_row[wid];
            y_dst[oi2] = __floats2half2_rn(w * vx, w * vy);
            float2 e = emb2[oi2];
            out2[oi2] = make_float2(e.x + vx, e.y + vy);
        } else if (mode == 1) {
            float w = inv_row[wid];
            y_dst[oi2] = __floats2half2_rn(w * vx, w * vy);
            float2 o = out2[oi2];
            out2[oi2] = make_float2(o.x + vx, o.y + vy);
        } else {
            float2 o = out2[oi2];
            out2[oi2] = make_float2((o.x + vx) * 0.25f, (o.y + vy) * 0.25f);
        }
    }
}

extern "C" void kernel_launch(void* const* d_in, const int* in_sizes, int n_in,
                              void* d_out, int out_size, void* d_ws, size_t ws_size,
                              hipStream_t stream) {
    const int*   edge_index = (const int*)d_in[0];   // [2, E]
    const float* embedding  = (const float*)d_in[1]; // [N, 64]
    const int* row = edge_index;
    const int* col = edge_index + NUM_EDGES;
    float* out = (float*)d_out;

    char* ws = (char*)d_ws;
    auto align_up = [](size_t v) { return (v + 255) & ~size_t(255); };
    size_t off = 0;
    int* cnt_row    = (int*)(ws + off); off = align_up(off + sizeof(int) * N_NODES);
    int* cnt_col    = (int*)(ws + off); off = align_up(off + sizeof(int) * N_NODES);
    int* col_ptr    = (int*)(ws + off); off = align_up(off + sizeof(int) * N_NODES);
    int* block_sums = (int*)(ws + off); off = align_up(off + sizeof(int) * 1024);
    int* sorted_src = (int*)(ws + off); off = align_up(off + sizeof(int) * NUM_EDGES);
    __half2* ya     = (__half2*)(ws + off); off = align_up(off + sizeof(__half2) * N_NODES * 32);
    __half2* yb     = (__half2*)(ws + off); off = align_up(off + sizeof(__half2) * N_NODES * 32);

    // 1) histograms
    hipMemsetAsync(cnt_row, 0, sizeof(int) * N_NODES, stream);
    hipMemsetAsync(cnt_col, 0, sizeof(int) * N_NODES, stream);
    {
        int threads = 256, blocks = (NUM_EDGES + threads - 1) / threads;
        hist_kernel<<<blocks, threads, 0, stream>>>(row, col, cnt_row, cnt_col);
    }
    // 2) exclusive scan of cnt_col -> col_ptr
    scan_block_sums<<<NUM_SCAN_BLOCKS, 256, 0, stream>>>(cnt_col, block_sums);
    scan_block_offsets<<<1, 256, 0, stream>>>(block_sums);
    scan_final<<<NUM_SCAN_BLOCKS, 256, 0, stream>>>(cnt_col, block_sums, col_ptr);
    // 3) counts -> rsqrt
    {
        int threads = 256, blocks = (N_NODES + threads - 1) / threads;
        inv_kernel<<<blocks, threads, 0, stream>>>(cnt_row, cnt_col);
    }
    const float* inv_row = (const float*)cnt_row;
    const float* inv_col = (const float*)cnt_col;
    // 4) counting-sort fill
    {
        int threads = 256, blocks = (NUM_EDGES + threads - 1) / threads;
        fill_kernel<<<blocks, threads, 0, stream>>>(row, col, col_ptr, sorted_src);
    }
    // 5) y0 = fp16(inv_row ⊙ emb)
    {
        int n2 = N_NODES * 32;
        int threads = 256, blocks = (n2 + threads - 1) / threads;
        init_y_kernel<<<blocks, threads, 0, stream>>>(inv_row, (const float2*)embedding, ya);
    }
    // 6) three gather layers (y ping-pong: ya -> yb -> ya)
    {
        int threads = 256;
        int blocks = (N_NODES * 64 + threads - 1) / threads;   // 37500
        layer_kernel<<<blocks, threads, 0, stream>>>(col_ptr, sorted_src, inv_row, inv_col,
                                                     ya, yb, (float2*)out,
                                                     (const float2*)embedding, 0);
        layer_kernel<<<blocks, threads, 0, stream>>>(col_ptr, sorted_src, inv_row, inv_col,
                                                     yb, ya, (float2*)out,
                                                     (const float2*)embedding, 1);
        layer_kernel<<<blocks, threads, 0, stream>>>(col_ptr, sorted_src, inv_row, inv_col,
                                                     ya, yb /*unused*/, (float2*)out,
                                                     (const float2*)embedding, 2);
    }
}

// Round 5
// 390.011 us; speedup vs baseline: 2.7684x; 1.1804x over previous
//
#include <hip/hip_runtime.h>
#include <hip/hip_fp16.h>

// LightGCN via padded direct-placement CSR (no histogram/scan for col) + fp16 gather layers.
// Scattered-request budget: build = 3.6M (row-cnt atomic, col-cursor atomic, placement write),
// layers = intrinsic gather requests.

constexpr int NUM_USERS = 100000;
constexpr int NUM_ITEMS = 50000;
constexpr int N_NODES   = NUM_USERS + NUM_ITEMS;   // 150000
constexpr int EMBED_DIM = 64;
constexpr int NUM_EDGES = 1200000;
constexpr int PAD = 64;                            // per-node bucket capacity (max degree << 64)

// ---- fused build: row histogram + col cursor + direct placement into padded CSR ----
// 4 edges per thread via int4 loads for more scattered requests in flight.
__global__ void build_kernel(const int4* __restrict__ row4, const int4* __restrict__ col4,
                             int* __restrict__ cnt_row, int* __restrict__ cnt_col,
                             int* __restrict__ sorted_pad) {
    int t = blockIdx.x * blockDim.x + threadIdx.x;
    if (t < NUM_EDGES / 4) {
        int4 r = row4[t];
        int4 c = col4[t];
        atomicAdd(&cnt_row[r.x], 1);
        atomicAdd(&cnt_row[r.y], 1);
        atomicAdd(&cnt_row[r.z], 1);
        atomicAdd(&cnt_row[r.w], 1);
        int p0 = atomicAdd(&cnt_col[c.x], 1);
        int p1 = atomicAdd(&cnt_col[c.y], 1);
        int p2 = atomicAdd(&cnt_col[c.z], 1);
        int p3 = atomicAdd(&cnt_col[c.w], 1);
        if (p0 < PAD) sorted_pad[(c.x << 6) | p0] = r.x;
        if (p1 < PAD) sorted_pad[(c.y << 6) | p1] = r.y;
        if (p2 < PAD) sorted_pad[(c.z << 6) | p2] = r.z;
        if (p3 < PAD) sorted_pad[(c.w << 6) | p3] = r.w;
    }
}

// ---- int counts -> rsqrt floats (separate outputs; cnt_col ints stay live for layer trip counts) ----
__global__ void inv_kernel(const int* __restrict__ cnt_row, const int* __restrict__ cnt_col,
                           float* __restrict__ inv_row, float* __restrict__ inv_col) {
    int i = blockIdx.x * blockDim.x + threadIdx.x;
    if (i < N_NODES) {
        int a = cnt_row[i];
        inv_row[i] = (a > 0) ? rsqrtf((float)a) : 0.0f;
        int b = cnt_col[i];
        inv_col[i] = (b > 0) ? rsqrtf((float)b) : 0.0f;
    }
}

// ---- y0 (fp16) = inv_row ⊙ emb ; one half2 (2 dims) per thread ----
__global__ void init_y_kernel(const float* __restrict__ inv_row,
                              const float2* __restrict__ emb2, __half2* __restrict__ y0) {
    int i = blockIdx.x * blockDim.x + threadIdx.x;     // over N*32
    if (i < N_NODES * (EMBED_DIM / 2)) {
        float w = inv_row[i >> 5];
        float2 e = emb2[i];
        y0[i] = __floats2half2_rn(w * e.x, w * e.y);
    }
}

// ---- one wave per destination node; padded CSR, single cooperative index load ----
// Lane layout: eh = lane>>5 (which of 2 concurrent edges), d2 = lane&31 (dim pair).
// v[c][:] = inv_col[c] * sum_{e: col=c} y[src_e][:]
// mode 0: y_dst = h(inv_row[c]*v); out = emb + v
// mode 1: y_dst = h(inv_row[c]*v); out += v
// mode 2: out = (out + v) * 0.25
__global__ void __launch_bounds__(256, 8)
layer_kernel(const int* __restrict__ cnt_col,
             const int* __restrict__ sorted_pad,
             const float* __restrict__ inv_row,
             const float* __restrict__ inv_col,
             const __half2* __restrict__ y_src,
             __half2* __restrict__ y_dst,
             float2* __restrict__ out2,
             const float2* __restrict__ emb2,
             int mode) {
    int wid  = (blockIdx.x * blockDim.x + threadIdx.x) >> 6;
    int lane = threadIdx.x & 63;
    if (wid >= N_NODES) return;
    int d2 = lane & 31;
    int eh = lane >> 5;
    int cnt = cnt_col[wid];
    if (cnt > PAD) cnt = PAD;
    // one coalesced 256B wave load of all indices; lanes >= cnt hold garbage (never dereferenced)
    int idx = sorted_pad[(wid << 6) | lane];

    float ax0 = 0.0f, ay0 = 0.0f, ax1 = 0.0f, ay1 = 0.0f;
    int j = 0;
    for (; j + 4 <= cnt; j += 4) {
        int sA = __shfl(idx, j + eh);          // edges j, j+1 across lane halves
        int sB = __shfl(idx, j + 2 + eh);      // edges j+2, j+3
        float2 vA = __half22float2(y_src[sA * 32 + d2]);
        float2 vB = __half22float2(y_src[sB * 32 + d2]);
        ax0 += vA.x; ay0 += vA.y;
        ax1 += vB.x; ay1 += vB.y;
    }
    for (; j < cnt; j += 2) {                  // tail 0..3 edges, predicated
        int jj = j + eh;
        int sA = __shfl(idx, (jj < cnt) ? jj : 0);   // lane 0 valid whenever cnt > 0
        float2 vA = __half22float2(y_src[sA * 32 + d2]);
        if (jj < cnt) { ax0 += vA.x; ay0 += vA.y; }
    }
    float sx = ax0 + ax1;
    float sy = ay0 + ay1;
    sx += __shfl_xor(sx, 32);                  // combine the two lane halves
    sy += __shfl_xor(sy, 32);

    float invc = inv_col[wid];
    float vx = sx * invc, vy = sy * invc;

    if (lane < 32) {
        int oi2 = wid * 32 + d2;
        if (mode == 0) {
            float w = inv_row[wid];
            y_dst[oi2] = __floats2half2_rn(w * vx, w * vy);
            float2 e = emb2[oi2];
            out2[oi2] = make_float2(e.x + vx, e.y + vy);
        } else if (mode == 1) {
            float w = inv_row[wid];
            y_dst[oi2] = __floats2half2_rn(w * vx, w * vy);
            float2 o = out2[oi2];
            out2[oi2] = make_float2(o.x + vx, o.y + vy);
        } else {
            float2 o = out2[oi2];
            out2[oi2] = make_float2((o.x + vx) * 0.25f, (o.y + vy) * 0.25f);
        }
    }
}

extern "C" void kernel_launch(void* const* d_in, const int* in_sizes, int n_in,
                              void* d_out, int out_size, void* d_ws, size_t ws_size,
                              hipStream_t stream) {
    const int*   edge_index = (const int*)d_in[0];   // [2, E]
    const float* embedding  = (const float*)d_in[1]; // [N, 64]
    const int* row = edge_index;
    const int* col = edge_index + NUM_EDGES;
    float* out = (float*)d_out;

    char* ws = (char*)d_ws;
    auto align_up = [](size_t v) { return (v + 255) & ~size_t(255); };
    size_t off = 0;
    int* cnt_row    = (int*)(ws + off); off = align_up(off + sizeof(int) * N_NODES);
    int* cnt_col    = (int*)(ws + off); off = align_up(off + sizeof(int) * N_NODES);
    float* inv_row  = (float*)(ws + off); off = align_up(off + sizeof(float) * N_NODES);
    float* inv_col  = (float*)(ws + off); off = align_up(off + sizeof(float) * N_NODES);
    int* sorted_pad = (int*)(ws + off); off = align_up(off + sizeof(int) * N_NODES * PAD);  // 38.4 MB
    __half2* ya     = (__half2*)(ws + off); off = align_up(off + sizeof(__half2) * N_NODES * 32);
    __half2* yb     = (__half2*)(ws + off); off = align_up(off + sizeof(__half2) * N_NODES * 32);
    // total ~79.3 MB

    // 1) zero the two count arrays (sorted_pad needs no init — only [0,cnt) slots are read)
    hipMemsetAsync(cnt_row, 0, sizeof(int) * N_NODES, stream);
    hipMemsetAsync(cnt_col, 0, sizeof(int) * N_NODES, stream);
    // 2) fused build
    {
        int threads = 256, blocks = (NUM_EDGES / 4 + threads - 1) / threads;   // 1172
        build_kernel<<<blocks, threads, 0, stream>>>((const int4*)row, (const int4*)col,
                                                     cnt_row, cnt_col, sorted_pad);
    }
    // 3) counts -> rsqrt
    {
        int threads = 256, blocks = (N_NODES + threads - 1) / threads;
        inv_kernel<<<blocks, threads, 0, stream>>>(cnt_row, cnt_col, inv_row, inv_col);
    }
    // 4) y0 = fp16(inv_row ⊙ emb)
    {
        int n2 = N_NODES * 32;
        int threads = 256, blocks = (n2 + threads - 1) / threads;
        init_y_kernel<<<blocks, threads, 0, stream>>>(inv_row, (const float2*)embedding, ya);
    }
    // 5) three gather layers (y ping-pong: ya -> yb -> ya)
    {
        int threads = 256;
        int blocks = (N_NODES * 64 + threads - 1) / threads;   // 37500
        layer_kernel<<<blocks, threads, 0, stream>>>(cnt_col, sorted_pad, inv_row, inv_col,
                                                     ya, yb, (float2*)out,
                                                     (const float2*)embedding, 0);
        layer_kernel<<<blocks, threads, 0, stream>>>(cnt_col, sorted_pad, inv_row, inv_col,
                                                     yb, ya, (float2*)out,
                                                     (const float2*)embedding, 1);
        layer_kernel<<<blocks, threads, 0, stream>>>(cnt_col, sorted_pad, inv_row, inv_col,
                                                     ya, yb /*unused*/, (float2*)out,
                                                     (const float2*)embedding, 2);
    }
}

// Round 6
// 311.186 us; speedup vs baseline: 3.4697x; 1.2533x over previous
//
#include <hip/hip_runtime.h>
#include <hip/hip_fp16.h>

// LightGCN, atomic-free CSR build:
//  pass1: bin edges by col>>10 (and row values by row>>10) with LDS histograms;
//         only 86K global atomics (per block x bucket run reservation) instead of 3.6M.
//  pass2: per-bucket LDS counting sort -> padded CSR + cnt/inv arrays (coalesced writes).
//  layers: fp16 y = inv_row (*) x gather, 2 edges per wave via lane halves.

constexpr int NUM_USERS = 100000;
constexpr int NUM_ITEMS = 50000;
constexpr int N_NODES   = NUM_USERS + NUM_ITEMS;   // 150000
constexpr int EMBED_DIM = 64;
constexpr int NUM_EDGES = 1200000;
constexpr int PAD   = 64;                          // per-node CSR capacity (max degree << 64)
constexpr int SHIFT = 10;                          // coarse bucket = node >> 10
constexpr int NBUCK = (N_NODES + (1 << SHIFT) - 1) >> SHIFT;   // 147
constexpr int CAPC  = 9216;                        // bucket capacity (Poisson mean 8163, sigma 90)
constexpr int EPB   = 4096;                        // edges per pass-1 block
constexpr int P1_BLOCKS = (NUM_EDGES + EPB - 1) / EPB;         // 293

// ---- pass 1: LDS-aggregated binning of (col,row) by col-bucket and row values by row-bucket ----
__global__ void __launch_bounds__(256)
pass1_bin(const int* __restrict__ row, const int* __restrict__ col,
          int* __restrict__ gcur_c, int* __restrict__ gcur_r,
          unsigned int* __restrict__ binned_c, unsigned short* __restrict__ binned_r) {
    __shared__ int hist_c[NBUCK], hist_r[NBUCK], cur_c[NBUCK], cur_r[NBUCK];
    int t = threadIdx.x;
    for (int i = t; i < NBUCK; i += 256) { hist_c[i] = 0; hist_r[i] = 0; }
    __syncthreads();
    int base = blockIdx.x * EPB;
    // phase A: per-block bucket counts (LDS atomics)
    for (int k = 0; k < EPB / 256; ++k) {
        int e = base + k * 256 + t;
        if (e < NUM_EDGES) {
            atomicAdd(&hist_c[col[e] >> SHIFT], 1);
            atomicAdd(&hist_r[row[e] >> SHIFT], 1);
        }
    }
    __syncthreads();
    // phase B: reserve contiguous runs in each bucket (one global atomic per block x bucket)
    for (int i = t; i < NBUCK; i += 256) {
        cur_c[i] = atomicAdd(&gcur_c[i], hist_c[i]);
        cur_r[i] = atomicAdd(&gcur_r[i], hist_r[i]);
    }
    __syncthreads();
    // phase C: scatter into bucket streams (LDS cursors give absolute in-bucket slots)
    for (int k = 0; k < EPB / 256; ++k) {
        int e = base + k * 256 + t;
        if (e < NUM_EDGES) {
            int c = col[e], r = row[e];
            int dc = c >> SHIFT;
            int sc = atomicAdd(&cur_c[dc], 1);
            if (sc < CAPC)
                binned_c[dc * CAPC + sc] = ((unsigned)(c & 1023) << 18) | (unsigned)r;
            int dr = r >> SHIFT;
            int sr = atomicAdd(&cur_r[dr], 1);
            if (sr < CAPC)
                binned_r[dr * CAPC + sr] = (unsigned short)(r & 1023);
        }
    }
}

// ---- pass 2: blocks 0..146 place col-buckets into padded CSR; blocks 147..293 row histograms ----
__global__ void __launch_bounds__(256)
pass2_place(const int* __restrict__ gcur_c, const int* __restrict__ gcur_r,
            const unsigned int* __restrict__ binned_c, const unsigned short* __restrict__ binned_r,
            int* __restrict__ sorted_pad, int* __restrict__ cnt_col,
            float* __restrict__ inv_col, float* __restrict__ inv_row) {
    __shared__ int cur[1 << SHIFT];
    int t = threadIdx.x;
    for (int i = t; i < (1 << SHIFT); i += 256) cur[i] = 0;
    __syncthreads();
    int b = blockIdx.x;
    if (b < NBUCK) {
        int n = gcur_c[b]; if (n > CAPC) n = CAPC;
        const unsigned int* src = binned_c + b * CAPC;
        for (int i = t; i < n; i += 256) {
            unsigned int w = src[i];
            int lc = w >> 18;
            int r  = (int)(w & 0x3FFFFu);
            int slot = atomicAdd(&cur[lc], 1);          // LDS cursor
            if (slot < PAD)
                sorted_pad[((((b << SHIFT) | lc)) << 6) | slot] = r;   // L2-resident window
        }
        __syncthreads();
        for (int i = t; i < (1 << SHIFT); i += 256) {
            int c = (b << SHIFT) | i;
            if (c < N_NODES) {
                int cnt = cur[i];
                cnt_col[c] = cnt;
                inv_col[c] = (cnt > 0) ? rsqrtf((float)cnt) : 0.0f;
            }
        }
    } else {
        int bb = b - NBUCK;
        int n = gcur_r[bb]; if (n > CAPC) n = CAPC;
        const unsigned short* src = binned_r + bb * CAPC;
        for (int i = t; i < n; i += 256) {
            atomicAdd(&cur[src[i]], 1);                 // LDS histogram
        }
        __syncthreads();
        for (int i = t; i < (1 << SHIFT); i += 256) {
            int c = (bb << SHIFT) | i;
            if (c < N_NODES) {
                int cnt = cur[i];
                inv_row[c] = (cnt > 0) ? rsqrtf((float)cnt) : 0.0f;
            }
        }
    }
}

// ---- y0 (fp16) = inv_row (*) emb ; one half2 (2 dims) per thread ----
__global__ void init_y_kernel(const float* __restrict__ inv_row,
                              const float2* __restrict__ emb2, __half2* __restrict__ y0) {
    int i = blockIdx.x * blockDim.x + threadIdx.x;     // over N*32
    if (i < N_NODES * (EMBED_DIM / 2)) {
        float w = inv_row[i >> 5];
        float2 e = emb2[i];
        y0[i] = __floats2half2_rn(w * e.x, w * e.y);
    }
}

// ---- one wave per destination node; padded CSR, single cooperative index load ----
// Lane layout: eh = lane>>5 (which of 2 concurrent edges), d2 = lane&31 (dim pair).
// mode 0: y_dst = h(inv_row[c]*v); out = emb + v
// mode 1: y_dst = h(inv_row[c]*v); out += v
// mode 2: out = (out + v) * 0.25
__global__ void __launch_bounds__(256, 8)
layer_kernel(const int* __restrict__ cnt_col,
             const int* __restrict__ sorted_pad,
             const float* __restrict__ inv_row,
             const float* __restrict__ inv_col,
             const __half2* __restrict__ y_src,
             __half2* __restrict__ y_dst,
             float2* __restrict__ out2,
             const float2* __restrict__ emb2,
             int mode) {
    int wid  = (blockIdx.x * blockDim.x + threadIdx.x) >> 6;
    int lane = threadIdx.x & 63;
    if (wid >= N_NODES) return;
    int d2 = lane & 31;
    int eh = lane >> 5;
    int cnt = cnt_col[wid];
    if (cnt > PAD) cnt = PAD;
    // one coalesced 256B wave load of all indices; lanes >= cnt hold garbage (never dereferenced)
    int idx = sorted_pad[(wid << 6) | lane];

    float ax0 = 0.0f, ay0 = 0.0f, ax1 = 0.0f, ay1 = 0.0f;
    int j = 0;
    for (; j + 4 <= cnt; j += 4) {
        int sA = __shfl(idx, j + eh);          // edges j, j+1 across lane halves
        int sB = __shfl(idx, j + 2 + eh);      // edges j+2, j+3
        float2 vA = __half22float2(y_src[sA * 32 + d2]);
        float2 vB = __half22float2(y_src[sB * 32 + d2]);
        ax0 += vA.x; ay0 += vA.y;
        ax1 += vB.x; ay1 += vB.y;
    }
    for (; j < cnt; j += 2) {                  // tail 0..3 edges, predicated
        int jj = j + eh;
        int sA = __shfl(idx, (jj < cnt) ? jj : 0);   // lane 0 valid whenever cnt > 0
        float2 vA = __half22float2(y_src[sA * 32 + d2]);
        if (jj < cnt) { ax0 += vA.x; ay0 += vA.y; }
    }
    float sx = ax0 + ax1;
    float sy = ay0 + ay1;
    sx += __shfl_xor(sx, 32);                  // combine the two lane halves
    sy += __shfl_xor(sy, 32);

    float invc = inv_col[wid];
    float vx = sx * invc, vy = sy * invc;

    if (lane < 32) {
        int oi2 = wid * 32 + d2;
        if (mode == 0) {
            float w = inv_row[wid];
            y_dst[oi2] = __floats2half2_rn(w * vx, w * vy);
            float2 e = emb2[oi2];
            out2[oi2] = make_float2(e.x + vx, e.y + vy);
        } else if (mode == 1) {
            float w = inv_row[wid];
            y_dst[oi2] = __floats2half2_rn(w * vx, w * vy);
            float2 o = out2[oi2];
            out2[oi2] = make_float2(o.x + vx, o.y + vy);
        } else {
            float2 o = out2[oi2];
            out2[oi2] = make_float2((o.x + vx) * 0.25f, (o.y + vy) * 0.25f);
        }
    }
}

extern "C" void kernel_launch(void* const* d_in, const int* in_sizes, int n_in,
                              void* d_out, int out_size, void* d_ws, size_t ws_size,
                              hipStream_t stream) {
    const int*   edge_index = (const int*)d_in[0];   // [2, E]
    const float* embedding  = (const float*)d_in[1]; // [N, 64]
    const int* row = edge_index;
    const int* col = edge_index + NUM_EDGES;
    float* out = (float*)d_out;

    char* ws = (char*)d_ws;
    auto align_up = [](size_t v) { return (v + 255) & ~size_t(255); };
    size_t off = 0;
    int* gcur_c     = (int*)(ws + off); off = align_up(off + sizeof(int) * NBUCK);
    int* gcur_r     = (int*)(ws + off); off = align_up(off + sizeof(int) * NBUCK);
    int* cnt_col    = (int*)(ws + off); off = align_up(off + sizeof(int) * N_NODES);
    float* inv_row  = (float*)(ws + off); off = align_up(off + sizeof(float) * N_NODES);
    float* inv_col  = (float*)(ws + off); off = align_up(off + sizeof(float) * N_NODES);
    int* sorted_pad = (int*)(ws + off); off = align_up(off + sizeof(int) * N_NODES * PAD);  // 38.4 MB
    __half2* ya     = (__half2*)(ws + off); off = align_up(off + sizeof(__half2) * N_NODES * 32);
    __half2* yb     = (__half2*)(ws + off); off = align_up(off + sizeof(__half2) * N_NODES * 32);
    // binned arrays alias yb: consumed by pass2 before yb's first write (layer 1)
    unsigned int*   binned_c = (unsigned int*)yb;                       // 5.4 MB
    unsigned short* binned_r = (unsigned short*)((char*)yb + align_up(sizeof(unsigned int) * NBUCK * CAPC)); // 2.7 MB
    // total ws ~78.6 MB

    // 1) zero the 294 bucket cursors (gcur_c and gcur_r are adjacent)
    hipMemsetAsync(gcur_c, 0, sizeof(int) * 2 * NBUCK + 256, stream);
    // 2) pass 1: bin edges
    pass1_bin<<<P1_BLOCKS, 256, 0, stream>>>(row, col, gcur_c, gcur_r, binned_c, binned_r);
    // 3) pass 2: place into padded CSR + cnt/inv arrays
    pass2_place<<<2 * NBUCK, 256, 0, stream>>>(gcur_c, gcur_r, binned_c, binned_r,
                                               sorted_pad, cnt_col, inv_col, inv_row);
    // 4) y0 = fp16(inv_row (*) emb)
    {
        int n2 = N_NODES * 32;
        int threads = 256, blocks = (n2 + threads - 1) / threads;
        init_y_kernel<<<blocks, threads, 0, stream>>>(inv_row, (const float2*)embedding, ya);
    }
    // 5) three gather layers (y ping-pong: ya -> yb -> ya)
    {
        int threads = 256;
        int blocks = (N_NODES * 64 + threads - 1) / threads;   // 37500
        layer_kernel<<<blocks, threads, 0, stream>>>(cnt_col, sorted_pad, inv_row, inv_col,
                                                     ya, yb, (float2*)out,
                                                     (const float2*)embedding, 0);
        layer_kernel<<<blocks, threads, 0, stream>>>(cnt_col, sorted_pad, inv_row, inv_col,
                                                     yb, ya, (float2*)out,
                                                     (const float2*)embedding, 1);
        layer_kernel<<<blocks, threads, 0, stream>>>(cnt_col, sorted_pad, inv_row, inv_col,
                                                     ya, yb /*unused*/, (float2*)out,
                                                     (const float2*)embedding, 2);
    }
}